// Round 1
// baseline (166.049 us; speedup 1.0000x reference)
//
#include <hip/hip_runtime.h>

#define N2V    34816
#define BATCH  2048
#define E1V    32768
#define KFAN   16
#define INDIM  128
#define HID    256
#define OUTD   128

// ws layout (floats): Wc1[256*256] @0, Wc2[512*128] @65536,
// bs1[256] @131072, bs2[128] @131328, h1[N2*256] @131456
#define OFF_WC1 0
#define OFF_WC2 65536
#define OFF_BS1 131072
#define OFF_BS2 131328
#define OFF_H1  131456

__global__ __launch_bounds__(256) void prepack_kernel(
    const float* __restrict__ W1n, const float* __restrict__ b1n,
    const float* __restrict__ W1h, const float* __restrict__ b1h,
    const float* __restrict__ W2n, const float* __restrict__ b2n,
    const float* __restrict__ W2h, const float* __restrict__ b2h,
    float* __restrict__ Wc1, float* __restrict__ Wc2,
    float* __restrict__ bs1, float* __restrict__ bs2) {
  int idx = blockIdx.x * 256 + threadIdx.x;  // 0..65535
  // Wc1[c][j] = (c<128) ? W1n[j][c] : W1h[j][c-128]
  int c1 = idx >> 8, j1 = idx & 255;
  Wc1[idx] = (c1 < 128) ? W1n[j1 * 128 + c1] : W1h[j1 * 128 + (c1 - 128)];
  // Wc2[c][j] = (c<256) ? W2n[j][c] : W2h[j][c-256]
  int c2 = idx >> 7, j2 = idx & 127;
  Wc2[idx] = (c2 < 256) ? W2n[j2 * 256 + c2] : W2h[j2 * 256 + (c2 - 256)];
  if (idx < 256) bs1[idx] = b1n[idx] + b1h[idx];
  if (idx < 128) bs2[idx] = b2n[idx] + b2h[idx];
}

// layer 1: per block, 16 nodes. Phase 1: gather-sum 16 neighbors (128 dims)
// + decayed self features into LDS z[16][256]. Phase 2: each of 256 threads
// computes column j of h1 for all 16 rows (z reads are wave-uniform broadcasts).
__global__ __launch_bounds__(256) void layer1_kernel(
    const float* __restrict__ x, const float* __restrict__ t2,
    const float* __restrict__ n_times2, const int* __restrict__ nodes2,
    const int* __restrict__ nbr2, const float* __restrict__ tk,
    const float* __restrict__ Wc1, const float* __restrict__ bs1,
    float* __restrict__ h1) {
  __shared__ float z[16][HID];  // 16 KiB
  const int t = threadIdx.x;
  const int i0 = blockIdx.x * 16;
  const int d = t & 127;
  const int rh = t >> 7;  // 0 or 1, wave-uniform
  const float tkv = tk[0];

  for (int r = rh; r < 16; r += 2) {
    const int i = i0 + r;
    const int* nb = nbr2 + i * KFAN;
    float s = 0.f;
#pragma unroll
    for (int k = 0; k < KFAN; ++k) {
      s += x[nb[k] * INDIM + d];
    }
    z[r][d] = s;
    const float dec = __expf(-tkv * (t2[i] - n_times2[i]));
    z[r][128 + d] = x[nodes2[i] * INDIM + d] * dec;
  }
  __syncthreads();

  const int j = t;
  float acc[16];
  const float b = bs1[j];
#pragma unroll
  for (int r = 0; r < 16; ++r) acc[r] = b;
  for (int c = 0; c < HID; ++c) {
    const float w = Wc1[c * HID + j];
#pragma unroll
    for (int r = 0; r < 16; ++r) acc[r] = fmaf(z[r][c], w, acc[r]);
  }
#pragma unroll
  for (int r = 0; r < 16; ++r) {
    h1[(i0 + r) * HID + j] = fmaxf(acc[r], 0.f);
  }
}

// layer 2: per block, 8 batch rows. Phase 1: segment-sum 16 h1 rows +
// decayed self h1 row into LDS z[8][512]. Phase 2: each of 128 threads
// computes output column j for all 8 rows.
__global__ __launch_bounds__(128) void layer2_kernel(
    const float* __restrict__ h1, const float* __restrict__ ts,
    const float* __restrict__ n_times1, const float* __restrict__ tk,
    const float* __restrict__ Wc2, const float* __restrict__ bs2,
    float* __restrict__ out) {
  __shared__ float z[8][2 * HID];  // 16 KiB
  const int t = threadIdx.x;
  const int b0 = blockIdx.x * 8;
  const float tkv = tk[0];

  for (int r = 0; r < 8; ++r) {
    const int b = b0 + r;
    const float dec = __expf(-tkv * (ts[b] - n_times1[b]));
#pragma unroll
    for (int ci = 0; ci < 2; ++ci) {
      const int c = t + ci * 128;  // 0..255
      float s = 0.f;
#pragma unroll
      for (int k = 0; k < KFAN; ++k) {
        s += h1[(b * KFAN + k) * HID + c];
      }
      z[r][c] = s;
      z[r][HID + c] = h1[(E1V + b) * HID + c] * dec;
    }
  }
  __syncthreads();

  const int j = t;
  float acc[8];
  const float bb = bs2[j];
#pragma unroll
  for (int r = 0; r < 8; ++r) acc[r] = bb;
  for (int c = 0; c < 2 * HID; ++c) {
    const float w = Wc2[c * OUTD + j];
#pragma unroll
    for (int r = 0; r < 8; ++r) acc[r] = fmaf(z[r][c], w, acc[r]);
  }
#pragma unroll
  for (int r = 0; r < 8; ++r) {
    out[(b0 + r) * OUTD + j] = fmaxf(acc[r], 0.f);
  }
}

extern "C" void kernel_launch(void* const* d_in, const int* in_sizes, int n_in,
                              void* d_out, int out_size, void* d_ws, size_t ws_size,
                              hipStream_t stream) {
  const float* x        = (const float*)d_in[0];
  const float* ts       = (const float*)d_in[1];
  const float* t2       = (const float*)d_in[2];
  const float* n_times1 = (const float*)d_in[3];
  const float* n_times2 = (const float*)d_in[4];
  const float* W1n      = (const float*)d_in[5];
  const float* b1n      = (const float*)d_in[6];
  const float* W1h      = (const float*)d_in[7];
  const float* b1h      = (const float*)d_in[8];
  const float* W2n      = (const float*)d_in[9];
  const float* b2n      = (const float*)d_in[10];
  const float* W2h      = (const float*)d_in[11];
  const float* b2h      = (const float*)d_in[12];
  const float* tk       = (const float*)d_in[13];
  const int*   nodes2   = (const int*)d_in[14];
  const int*   nbr2     = (const int*)d_in[15];
  // d_in[16] = seg2, d_in[17] = seg1 — implicit (row-major repeat layout)

  float* ws  = (float*)d_ws;
  float* Wc1 = ws + OFF_WC1;
  float* Wc2 = ws + OFF_WC2;
  float* bs1 = ws + OFF_BS1;
  float* bs2 = ws + OFF_BS2;
  float* h1  = ws + OFF_H1;
  float* out = (float*)d_out;

  prepack_kernel<<<256, 256, 0, stream>>>(W1n, b1n, W1h, b1h, W2n, b2n, W2h, b2h,
                                          Wc1, Wc2, bs1, bs2);
  layer1_kernel<<<N2V / 16, 256, 0, stream>>>(x, t2, n_times2, nodes2, nbr2, tk,
                                              Wc1, bs1, h1);
  layer2_kernel<<<BATCH / 8, 128, 0, stream>>>(h1, ts, n_times1, tk, Wc2, bs2, out);
}

// Round 2
// 118.126 us; speedup vs baseline: 1.4057x; 1.4057x over previous
//
#include <hip/hip_runtime.h>
#include <hip/hip_bf16.h>

#define N2V    34816
#define BATCH  2048
#define E1V    32768
#define KFAN   16
#define INDIM  128
#define HID    256
#define OUTD   128

// ws layout (float units):
//   Wc2  [512*128] f32   @ 0
//   bs1  [256]     f32   @ 65536
//   bs2  [128]     f32   @ 65792
//   Wc1b [256*256] bf16  @ 65920   (32768 floats worth)
//   h1   [N2*256]  f32   @ 98688
#define OFF_WC2  0
#define OFF_BS1  65536
#define OFF_BS2  65792
#define OFF_WC1B 65920
#define OFF_H1   98688

typedef __attribute__((ext_vector_type(8))) short bf16x8;
typedef __attribute__((ext_vector_type(4))) float f32x4;

__global__ __launch_bounds__(256) void prepack_kernel(
    const float* __restrict__ W1n, const float* __restrict__ b1n,
    const float* __restrict__ W1h, const float* __restrict__ b1h,
    const float* __restrict__ W2n, const float* __restrict__ b2n,
    const float* __restrict__ W2h, const float* __restrict__ b2h,
    __hip_bfloat16* __restrict__ Wc1b, float* __restrict__ Wc2,
    float* __restrict__ bs1, float* __restrict__ bs2) {
  int idx = blockIdx.x * 256 + threadIdx.x;  // 0..65535
  // Wc1b[j][c] = (c<128) ? W1n[j][c] : W1h[j][c-128]   (bf16, B-operand layout)
  int j1 = idx >> 8, c1 = idx & 255;
  float v1 = (c1 < 128) ? W1n[j1 * 128 + c1] : W1h[j1 * 128 + (c1 - 128)];
  Wc1b[idx] = __float2bfloat16(v1);
  // Wc2[c][j] = (c<256) ? W2n[j][c] : W2h[j][c-256]    (f32)
  int c2 = idx >> 7, j2 = idx & 127;
  Wc2[idx] = (c2 < 256) ? W2n[j2 * 256 + c2] : W2h[j2 * 256 + (c2 - 256)];
  if (idx < 256) bs1[idx] = b1n[idx] + b1h[idx];
  if (idx < 128) bs2[idx] = b2n[idx] + b2h[idx];
}

// layer 1: 32 nodes per block, 256 threads (4 waves).
// Phase 1: gather-sum 16 neighbors + decayed self feats -> bf16 LDS z[32][264].
// Phase 2: MFMA 32x256 = (2 m-tiles) x (4 waves x 4 n-tiles), K=256 (8 steps).
__global__ __launch_bounds__(256) void layer1_kernel(
    const float* __restrict__ x, const float* __restrict__ t2,
    const float* __restrict__ n_times2, const int* __restrict__ nodes2,
    const int* __restrict__ nbr2, const float* __restrict__ tk,
    const __hip_bfloat16* __restrict__ Wc1b, const float* __restrict__ bs1,
    float* __restrict__ h1) {
  __shared__ __hip_bfloat16 z[32][264];  // pad +8 bf16: row stride 528B (132 dw, 4 mod 32)
  const int t = threadIdx.x;
  const int i0 = blockIdx.x * 32;
  const int d = t & 127;
  const int rh = t >> 7;  // 0 or 1 (wave-uniform)
  const float tkv = tk[0];

  for (int r = rh; r < 32; r += 2) {
    const int i = i0 + r;
    const int* nb = nbr2 + i * KFAN;
    float s = 0.f;
#pragma unroll
    for (int k = 0; k < KFAN; ++k) {
      s += x[nb[k] * INDIM + d];
    }
    z[r][d] = __float2bfloat16(s);
    const float dec = __expf(-tkv * (t2[i] - n_times2[i]));
    z[r][128 + d] = __float2bfloat16(x[nodes2[i] * INDIM + d] * dec);
  }
  __syncthreads();

  const int wid = t >> 6;       // 0..3 -> owns cols [wid*64, wid*64+64)
  const int lane = t & 63;
  const int lr = lane & 15;     // A row-in-tile / B col-in-tile
  const int lk8 = (lane >> 4) * 8;
  const int ncol0 = wid * 64;

  f32x4 acc[2][4];
#pragma unroll
  for (int m = 0; m < 2; ++m)
#pragma unroll
    for (int n = 0; n < 4; ++n) acc[m][n] = (f32x4){0.f, 0.f, 0.f, 0.f};

#pragma unroll
  for (int ks = 0; ks < 8; ++ks) {
    const int kb = ks * 32 + lk8;
    bf16x8 a0 = *reinterpret_cast<const bf16x8*>(&z[lr][kb]);
    bf16x8 a1 = *reinterpret_cast<const bf16x8*>(&z[16 + lr][kb]);
#pragma unroll
    for (int nt = 0; nt < 4; ++nt) {
      const int col = ncol0 + nt * 16 + lr;
      bf16x8 b = *reinterpret_cast<const bf16x8*>(&Wc1b[col * HID + kb]);
      acc[0][nt] = __builtin_amdgcn_mfma_f32_16x16x32_bf16(a0, b, acc[0][nt], 0, 0, 0);
      acc[1][nt] = __builtin_amdgcn_mfma_f32_16x16x32_bf16(a1, b, acc[1][nt], 0, 0, 0);
    }
  }

  // C/D layout: col = lane&15, row = (lane>>4)*4 + reg
  const int orow = (lane >> 4) * 4;
#pragma unroll
  for (int nt = 0; nt < 4; ++nt) {
    const int col = ncol0 + nt * 16 + lr;
    const float bias = bs1[col];
#pragma unroll
    for (int mt = 0; mt < 2; ++mt) {
#pragma unroll
      for (int q = 0; q < 4; ++q) {
        const int row = i0 + mt * 16 + orow + q;
        h1[row * HID + col] = fmaxf(acc[mt][nt][q] + bias, 0.f);
      }
    }
  }
}

// layer 2: 8 batch rows per block, 256 threads.
// Phase 1: contiguous 16-row segment sum + decayed self -> LDS z[8][516(pad)].
// Phase 2: register-tiled fp32 GEMM: thread owns (row r = t>>5, 4 cols).
__global__ __launch_bounds__(256) void layer2_kernel(
    const float* __restrict__ h1, const float* __restrict__ ts,
    const float* __restrict__ n_times1, const float* __restrict__ tk,
    const float* __restrict__ Wc2, const float* __restrict__ bs2,
    float* __restrict__ out) {
  __shared__ float z[8][516];  // pad +4 dwords
  const int t = threadIdx.x;
  const int b0 = blockIdx.x * 8;
  const float tkv = tk[0];

  const int c = t;  // 0..255
  for (int r = 0; r < 8; ++r) {
    const int b = b0 + r;
    const float dec = __expf(-tkv * (ts[b] - n_times1[b]));
    float s = 0.f;
#pragma unroll
    for (int k = 0; k < KFAN; ++k) {
      s += h1[(b * KFAN + k) * HID + c];
    }
    z[r][c] = s;
    z[r][HID + c] = h1[(E1V + b) * HID + c] * dec;
  }
  __syncthreads();

  const int r = t >> 5;          // 0..7
  const int jt = (t & 31) * 4;   // 0..124
  const float4 bb = *reinterpret_cast<const float4*>(&bs2[jt]);
  float4 acc = bb;
#pragma unroll 4
  for (int cc = 0; cc < 2 * HID; ++cc) {
    const float zv = z[r][cc];
    const float4 w = *reinterpret_cast<const float4*>(&Wc2[cc * OUTD + jt]);
    acc.x = fmaf(zv, w.x, acc.x);
    acc.y = fmaf(zv, w.y, acc.y);
    acc.z = fmaf(zv, w.z, acc.z);
    acc.w = fmaf(zv, w.w, acc.w);
  }
  float4 res;
  res.x = fmaxf(acc.x, 0.f);
  res.y = fmaxf(acc.y, 0.f);
  res.z = fmaxf(acc.z, 0.f);
  res.w = fmaxf(acc.w, 0.f);
  *reinterpret_cast<float4*>(&out[(b0 + r) * OUTD + jt]) = res;
}

extern "C" void kernel_launch(void* const* d_in, const int* in_sizes, int n_in,
                              void* d_out, int out_size, void* d_ws, size_t ws_size,
                              hipStream_t stream) {
  const float* x        = (const float*)d_in[0];
  const float* ts       = (const float*)d_in[1];
  const float* t2       = (const float*)d_in[2];
  const float* n_times1 = (const float*)d_in[3];
  const float* n_times2 = (const float*)d_in[4];
  const float* W1n      = (const float*)d_in[5];
  const float* b1n      = (const float*)d_in[6];
  const float* W1h      = (const float*)d_in[7];
  const float* b1h      = (const float*)d_in[8];
  const float* W2n      = (const float*)d_in[9];
  const float* b2n      = (const float*)d_in[10];
  const float* W2h      = (const float*)d_in[11];
  const float* b2h      = (const float*)d_in[12];
  const float* tk       = (const float*)d_in[13];
  const int*   nodes2   = (const int*)d_in[14];
  const int*   nbr2     = (const int*)d_in[15];
  // d_in[16] = seg2, d_in[17] = seg1 — implicit (row-major repeat layout)

  float* ws   = (float*)d_ws;
  float* Wc2  = ws + OFF_WC2;
  float* bs1  = ws + OFF_BS1;
  float* bs2  = ws + OFF_BS2;
  __hip_bfloat16* Wc1b = (__hip_bfloat16*)(ws + OFF_WC1B);
  float* h1   = ws + OFF_H1;
  float* out  = (float*)d_out;

  prepack_kernel<<<256, 256, 0, stream>>>(W1n, b1n, W1h, b1h, W2n, b2n, W2h, b2h,
                                          Wc1b, Wc2, bs1, bs2);
  layer1_kernel<<<N2V / 32, 256, 0, stream>>>(x, t2, n_times2, nodes2, nbr2, tk,
                                              Wc1b, bs1, h1);
  layer2_kernel<<<BATCH / 8, 256, 0, stream>>>(h1, ts, n_times1, tk, Wc2, bs2, out);
}